// Round 6
// baseline (183.681 us; speedup 1.0000x reference)
//
#include <hip/hip_runtime.h>

// Problem constants (from reference setup_inputs)
#define BB   8
#define PP   16384
#define KK   16384
#define NN   16
#define CIN  64
#define REL  3
#define CC   67            // CIN + REL
#define OUTC 64
#define KPAD 96            // MFMA K dim: 64 feat + 3 rel + 29 zero pad
#define PITCH_US 104       // ushorts per LDS row: 96 data + 8 pad = 208 B

// History: r2-r4 plateaued at 94us (DS-pipe: compiler re-read 67-elem W row
// per row). r5 moved the matvec to MFMA: 76us, but ALL pipes idle (VALU 27%,
// MFMA 0.8%, HBM 22%, occupancy 35%) -> latency-bound: per-row serial chain
// s_load(idx/valid) -> 16 gathers -> fma chain, rows sequential, ~11 waves/CU.
//
// Round 6: attack latency with concurrency.
//  * Phase 1 processes ROW PAIRS with independent accumulators: 32 gathers
//    + two rows' scalar metadata in flight per chain segment (2x MLP).
//  * Occupancy 16 -> 24 waves/CU: __launch_bounds__(256,6) (VGPR cap ~84;
//    r5 used 52) + 1 group/wave + 2048 blocks so dispatch can backfill
//    (r5's exact-4-blocks/CU grid time-averaged only 35% occupancy).
//  * Dropped the B-frag asm pin: never held (VGPR 52), and re-reading 12
//    ds_read_b128 per 16-row group is ~150 DS cyc - noise.
// Verified keepers: XCD<->batch binding (FETCH 255->102MB), wave-private
// bf16 staging tile + 16x16x32 bf16 MFMA matvec (absmax 0.0156 vs 0.0725).

typedef short s16x8 __attribute__((ext_vector_type(8)));   // 8 bf16 = 4 VGPRs
typedef float f32x4 __attribute__((ext_vector_type(4)));   // MFMA accum

static __device__ __forceinline__ unsigned short bf16_rne(float f) {
    unsigned int u = __float_as_uint(f);
    u += 0x7FFF + ((u >> 16) & 1);          // round-to-nearest-even
    return (unsigned short)(u >> 16);
}

__global__ __launch_bounds__(256, 6) void graphconv_kernel(
    const float* __restrict__ feats,         // [B, P, CIN]
    const int*   __restrict__ n_idxs,        // [B, K, N]
    const float* __restrict__ neighbor_rel,  // [B, K, N, REL]
    const int*   __restrict__ neighbor_valid,// [B, K, N]
    const float* __restrict__ Wm,            // [OUTC, CC]
    const float* __restrict__ bvec,          // [OUTC]
    float*       __restrict__ out)           // [B, K, OUTC]
{
    // bf16 W image, B-layout: Wbf[o][k], k=0..66 = W[o][k], 67.. = 0
    __shared__ __align__(16) unsigned short Wbf[OUTC * PITCH_US];     // 13312 B
    // per-wave 16-row staging tiles (wave-private -> no barriers)
    __shared__ __align__(16) unsigned short Stile[4 * 16 * PITCH_US]; // 13312 B

    const int tid = threadIdx.x;

    // ---- one-time: W -> bf16 into LDS (dword writes, 2 cols each) ----
    {
        unsigned int* w32 = (unsigned int*)Wbf;
        for (int j = tid; j < OUTC * (PITCH_US / 2); j += 256) {
            const int o = j / (PITCH_US / 2);
            const int d = j - o * (PITCH_US / 2);
            const int c0 = 2 * d, c1 = 2 * d + 1;
            const float w0 = (c0 < CC) ? Wm[o * CC + c0] : 0.0f;
            const float w1 = (c1 < CC) ? Wm[o * CC + c1] : 0.0f;
            w32[j] = (unsigned int)bf16_rne(w0) |
                     ((unsigned int)bf16_rne(w1) << 16);
        }
    }
    __syncthreads();

    const int lane = tid & 63;
    const int wave = __builtin_amdgcn_readfirstlane(tid >> 6);
    unsigned short* Sw = &Stile[wave * 16 * PITCH_US];

    // zero own tile once (pad cols 67..95 must be 0.0)
    {
        unsigned int* s32 = (unsigned int*)Sw;
        for (int j = lane; j < 16 * (PITCH_US / 2); j += 64) s32[j] = 0u;
    }

    const int b   = blockIdx.x & 7;          // XCD-bound batch (verified win)
    const int bib = blockIdx.x >> 3;         // block index within batch
    const float* fb = feats + (size_t)b * ((size_t)PP * CIN);

    const int kbase = (bib * 4 + wave) * 16; // this wave's 16 rows

    // ---- phase 1: gather+masked-sum, TWO rows in flight per iteration ----
    for (int ip = 0; ip < 8; ++ip) {
        const int iA = 2 * ip, iB = 2 * ip + 1;
        const size_t rowA = (size_t)b * KK + (size_t)(kbase + iA);
        const size_t rowB = rowA + 1;
        const int*   idxA = n_idxs         + rowA * NN;         // uniform
        const int*   idxB = n_idxs         + rowB * NN;
        const int*   vpA  = neighbor_valid + rowA * NN;         // uniform
        const int*   vpB  = neighbor_valid + rowB * NN;
        const float* relA = neighbor_rel   + rowA * (NN * REL); // uniform
        const float* relB = neighbor_rel   + rowB * (NN * REL);

        float sumA = 0.f, a0 = 0.f, a1 = 0.f, a2 = 0.f;
        float sumB = 0.f, b0 = 0.f, b1 = 0.f, b2 = 0.f;
        int cntA = 0, cntB = 0;
#pragma unroll
        for (int n = 0; n < NN; ++n) {
            const int   vA = vpA[n],  vB = vpB[n];     // uniform s_loads
            const int   dA = idxA[n], dB = idxB[n];    // uniform s_loads
            const float mA = (float)vA, mB = (float)vB;
            const float gA = fb[(size_t)dA * CIN + lane];  // 256B gathers,
            const float gB = fb[(size_t)dB * CIN + lane];  // 32 in flight
            sumA = fmaf(mA, gA, sumA);
            sumB = fmaf(mB, gB, sumB);
            a0 = fmaf(mA, relA[n * 3 + 0], a0);
            a1 = fmaf(mA, relA[n * 3 + 1], a1);
            a2 = fmaf(mA, relA[n * 3 + 2], a2);
            b0 = fmaf(mB, relB[n * 3 + 0], b0);
            b1 = fmaf(mB, relB[n * 3 + 1], b1);
            b2 = fmaf(mB, relB[n * 3 + 2], b2);
            cntA += vA; cntB += vB;
        }
        const float invA = (cntA > 0) ? (1.0f / (float)cntA) : 0.0f;
        const float invB = (cntB > 0) ? (1.0f / (float)cntB) : 0.0f;

        Sw[iA * PITCH_US + lane] = bf16_rne(sumA * invA);   // lane=channel
        Sw[iB * PITCH_US + lane] = bf16_rne(sumB * invB);
        if (lane < 3) {                                     // rel -> ch 64..66
            const float rA = (lane == 0) ? a0 : ((lane == 1) ? a1 : a2);
            const float rB = (lane == 0) ? b0 : ((lane == 1) ? b1 : b2);
            Sw[iA * PITCH_US + 64 + lane] = bf16_rne(rA * invA);
            Sw[iB * PITCH_US + 64 + lane] = bf16_rne(rB * invB);
        }
    }

    // ---- phase 2: 16x64 = S(16x96) x W^T(96x64) on the MFMA pipe ----
    f32x4 C0 = {0.f,0.f,0.f,0.f}, C1 = {0.f,0.f,0.f,0.f};
    f32x4 C2 = {0.f,0.f,0.f,0.f}, C3 = {0.f,0.f,0.f,0.f};
#pragma unroll
    for (int q = 0; q < 3; ++q) {
        // A[m][k]: m=lane&15, k=q*32+(lane>>4)*8+j  (16B aligned read)
        const s16x8 A = *(const s16x8*)&Sw[(lane & 15) * PITCH_US
                                           + q * 32 + (lane >> 4) * 8];
        const int ko = q * 32 + (lane >> 4) * 8;
        const s16x8 B0 = *(const s16x8*)&Wbf[( 0 + (lane & 15)) * PITCH_US + ko];
        const s16x8 B1 = *(const s16x8*)&Wbf[(16 + (lane & 15)) * PITCH_US + ko];
        const s16x8 B2 = *(const s16x8*)&Wbf[(32 + (lane & 15)) * PITCH_US + ko];
        const s16x8 B3 = *(const s16x8*)&Wbf[(48 + (lane & 15)) * PITCH_US + ko];
        C0 = __builtin_amdgcn_mfma_f32_16x16x32_bf16(A, B0, C0, 0, 0, 0);
        C1 = __builtin_amdgcn_mfma_f32_16x16x32_bf16(A, B1, C1, 0, 0, 0);
        C2 = __builtin_amdgcn_mfma_f32_16x16x32_bf16(A, B2, C2, 0, 0, 0);
        C3 = __builtin_amdgcn_mfma_f32_16x16x32_bf16(A, B3, C3, 0, 0, 0);
    }

    // ---- epilogue: C/D layout col=lane&15 (=outch%16), row=(lane>>4)*4+r
    const float bias0 = bvec[ 0 + (lane & 15)];
    const float bias1 = bvec[16 + (lane & 15)];
    const float bias2 = bvec[32 + (lane & 15)];
    const float bias3 = bvec[48 + (lane & 15)];
    const int m0 = (lane >> 4) * 4;
    const int oc = lane & 15;
#pragma unroll
    for (int r = 0; r < 4; ++r) {
        const size_t orow = ((size_t)b * KK + (size_t)(kbase + m0 + r)) * OUTC;
        out[orow + 0  + oc] = fmaxf(C0[r] + bias0, 0.0f);
        out[orow + 16 + oc] = fmaxf(C1[r] + bias1, 0.0f);
        out[orow + 32 + oc] = fmaxf(C2[r] + bias2, 0.0f);
        out[orow + 48 + oc] = fmaxf(C3[r] + bias3, 0.0f);
    }
}

extern "C" void kernel_launch(void* const* d_in, const int* in_sizes, int n_in,
                              void* d_out, int out_size, void* d_ws, size_t ws_size,
                              hipStream_t stream) {
    // setup_inputs order: keys(0), points(1), feats(2), n_idxs(3),
    // neighbor_rel(4), neighbor_valid(5), W(6), b(7). keys/points unused.
    const float* feats = (const float*)d_in[2];
    const int*   nidx  = (const int*)  d_in[3];
    const float* nrel  = (const float*)d_in[4];
    const int*   nval  = (const int*)  d_in[5];
    const float* Wm    = (const float*)d_in[6];
    const float* bv    = (const float*)d_in[7];
    float* out = (float*)d_out;

    // 2048 blocks = 256 per batch (b = blockIdx&7 -> XCD binding).
    // 4 waves/block x 16 rows/wave x 2048 blocks = 131072 rows.
    // 8 blocks/CU of work vs 6 resident (launch_bounds cap) -> backfill slack.
    graphconv_kernel<<<dim3(2048), dim3(256), 0, stream>>>(
        feats, nidx, nrel, nval, Wm, bv, out);
}

// Round 7
// 161.357 us; speedup vs baseline: 1.1384x; 1.1384x over previous
//
#include <hip/hip_runtime.h>

// Problem constants (from reference setup_inputs)
#define BB   8
#define PP   16384
#define KK   16384
#define NN   16
#define CIN  64
#define REL  3
#define CC   67
#define OUTC 64
#define PITCH_US 104       // ushorts per staged row: 96 data + 8 pad = 208 B

// History: r2-4 94us (compiler re-read W from LDS per row); r5 76us MFMA
// matvec, all pipes idle (latency); r6 87us REGRESSION (tail: 8 blocks work
// / 6 resident; + more waves contending the same TA port).
// Diagnosis: 16 wave64 dword-gather instrs per row is the hidden floor --
// each spans 4 cachelines; ~8 TA cyc/instr x 8192 instr/CU = 27us of pure
// address processing, serialized per row chain.
//
// Round 7: QUAD-ROW gather. lane = (sub = lane>>4 = row-in-quad,
// q = lane&15 = channel quarter). One global_load_dwordx4 serves one
// neighbor of each of 4 rows (16 lanes x 16B = one 256B feat row) ->
// 4 gather instrs/row (4x fewer), chains 4x shorter, same bytes.
//  * metadata: coalesced per-lane vector loads (lane l holds idx/valid/rel
//    of (row l/16, neighbor l%16)); packed id|v<<14; per-neighbor broadcast
//    within 16-lane segment via ONE ds_bpermute.
//  * rel sums + count: premultiply by own mask, 4-step ds_swizzle butterfly
//    (xor 1/2/4/8, segments stay inside 32-lane swizzle groups) -- replaces
//    48 redundant fma/row + all scalar metadata streams.
//  * phase 2 MFMA + epilogue unchanged (verified r5/r6, absmax 0.0156).
//  * grid 1024 blocks exact-fit (4/CU, launch_bounds(256,4), no r6 tail).

typedef short s16x8 __attribute__((ext_vector_type(8)));   // 8 bf16 = 4 VGPRs
typedef float f32x4 __attribute__((ext_vector_type(4)));   // MFMA accum
typedef unsigned int u32x2 __attribute__((ext_vector_type(2)));

static __device__ __forceinline__ unsigned short bf16_rne(float f) {
    unsigned int u = __float_as_uint(f);
    u += 0x7FFF + ((u >> 16) & 1);          // round-to-nearest-even
    return (unsigned short)(u >> 16);
}

static __device__ __forceinline__ float swz_add1(float v) {
    return v + __int_as_float(__builtin_amdgcn_ds_swizzle(__float_as_int(v), 0x041F));
}
static __device__ __forceinline__ float swz_add2(float v) {
    return v + __int_as_float(__builtin_amdgcn_ds_swizzle(__float_as_int(v), 0x081F));
}
static __device__ __forceinline__ float swz_add4(float v) {
    return v + __int_as_float(__builtin_amdgcn_ds_swizzle(__float_as_int(v), 0x101F));
}
static __device__ __forceinline__ float swz_add8(float v) {
    return v + __int_as_float(__builtin_amdgcn_ds_swizzle(__float_as_int(v), 0x201F));
}

__global__ __launch_bounds__(256, 4) void graphconv_kernel(
    const float* __restrict__ feats,         // [B, P, CIN]
    const int*   __restrict__ n_idxs,        // [B, K, N]
    const float* __restrict__ neighbor_rel,  // [B, K, N, REL]
    const int*   __restrict__ neighbor_valid,// [B, K, N]
    const float* __restrict__ Wm,            // [OUTC, CC]
    const float* __restrict__ bvec,          // [OUTC]
    float*       __restrict__ out)           // [B, K, OUTC]
{
    __shared__ __align__(16) unsigned short Wbf[OUTC * PITCH_US];     // 13312 B
    __shared__ __align__(16) unsigned short Stile[4 * 16 * PITCH_US]; // 13312 B

    const int tid = threadIdx.x;

    // ---- one-time: W -> bf16 into LDS, B-layout, cols 67..95 zeroed ----
    {
        unsigned int* w32 = (unsigned int*)Wbf;
        for (int j = tid; j < OUTC * (PITCH_US / 2); j += 256) {
            const int o = j / (PITCH_US / 2);
            const int d = j - o * (PITCH_US / 2);
            const int c0 = 2 * d, c1 = 2 * d + 1;
            const float w0 = (c0 < CC) ? Wm[o * CC + c0] : 0.0f;
            const float w1 = (c1 < CC) ? Wm[o * CC + c1] : 0.0f;
            w32[j] = (unsigned int)bf16_rne(w0) |
                     ((unsigned int)bf16_rne(w1) << 16);
        }
    }
    __syncthreads();

    const int lane = tid & 63;
    const int wave = __builtin_amdgcn_readfirstlane(tid >> 6);
    unsigned short* Sw = &Stile[wave * 16 * PITCH_US];

    // zero own tile once (pad cols 68..95 must stay 0.0 for the MFMA)
    {
        unsigned int* s32 = (unsigned int*)Sw;
        for (int j = lane; j < 16 * (PITCH_US / 2); j += 64) s32[j] = 0u;
    }

    const int b   = blockIdx.x & 7;          // XCD-bound batch (verified)
    const int bib = blockIdx.x >> 3;
    const float* fb = feats + (size_t)b * ((size_t)PP * CIN);

    const int q     = lane & 15;             // channel quarter (cols 4q..4q+3)
    const int permb = (lane & 48) << 2;      // byte index of segment start

    const int kw = (bib * 4 + wave) * 32;    // wave's first k (32 rows/wave)

    for (int g = 0; g < 2; ++g) {
        const int kg = kw + g * 16;

        // ---- phase 1: 4 quads of 4 rows -> bf16 staging tile ----
        for (int qd = 0; qd < 4; ++qd) {
            const size_t rq = (size_t)b * KK + (size_t)(kg + qd * 4);

            // per-lane metadata: lane l owns (row l/16, neighbor l%16)
            const int   vld = neighbor_valid[rq * NN + lane]; // 256B coalesced
            const int   idd = n_idxs[rq * NN + lane];         // 256B coalesced
            const int   cmb = idd | (vld << 14);              // id<16384 fits
            const float msf = (float)vld;
            const float* relq = neighbor_rel + rq * (NN * REL);
            float mr0 = msf * relq[3 * lane + 0];             // 768B coalesced
            float mr1 = msf * relq[3 * lane + 1];
            float mr2 = msf * relq[3 * lane + 2];
            float cnt = msf;

            float s0 = 0.f, s1 = 0.f, s2 = 0.f, s3 = 0.f;
#pragma unroll
            for (int n = 0; n < NN; ++n) {
                // broadcast (id,mask) of neighbor n of MY row from lane
                // (sub*16 + n) -- one ds_bpermute of the packed word
                const int cm = __builtin_amdgcn_ds_bpermute(permb + 4 * n, cmb);
                const float m = (float)(cm >> 14);            // 0.0 / 1.0
                const int  off = ((cm & 0x3FFF) << 6) + 4 * q; // element offset
                const float4 gv = *(const float4*)(fb + off);  // 16B/lane
                s0 = fmaf(m, gv.x, s0);
                s1 = fmaf(m, gv.y, s1);
                s2 = fmaf(m, gv.z, s2);
                s3 = fmaf(m, gv.w, s3);
            }

            // segment(16-lane) butterfly: count + 3 masked rel sums
            cnt = swz_add1(cnt); mr0 = swz_add1(mr0);
            mr1 = swz_add1(mr1); mr2 = swz_add1(mr2);
            cnt = swz_add2(cnt); mr0 = swz_add2(mr0);
            mr1 = swz_add2(mr1); mr2 = swz_add2(mr2);
            cnt = swz_add4(cnt); mr0 = swz_add4(mr0);
            mr1 = swz_add4(mr1); mr2 = swz_add4(mr2);
            cnt = swz_add8(cnt); mr0 = swz_add8(mr0);
            mr1 = swz_add8(mr1); mr2 = swz_add8(mr2);

            const float inv = (cnt > 0.f) ? (1.0f / cnt) : 0.0f;

            const int rowl = qd * 4 + (lane >> 4);   // row within 16-row tile
            u32x2 pv;
            pv.x = (unsigned)bf16_rne(s0 * inv) |
                   ((unsigned)bf16_rne(s1 * inv) << 16);
            pv.y = (unsigned)bf16_rne(s2 * inv) |
                   ((unsigned)bf16_rne(s3 * inv) << 16);
            *(u32x2*)(&Sw[rowl * PITCH_US + 4 * q]) = pv;     // ds_write_b64
            if (q == 0) {                      // rel -> ch 64..66 (+0 pad 67)
                u32x2 ev;
                ev.x = (unsigned)bf16_rne(mr0 * inv) |
                       ((unsigned)bf16_rne(mr1 * inv) << 16);
                ev.y = (unsigned)bf16_rne(mr2 * inv);
                *(u32x2*)(&Sw[rowl * PITCH_US + 64]) = ev;
            }
        }

        // ---- phase 2: 16x64 = S(16x96) x W^T(96x64) on the MFMA pipe ----
        f32x4 C0 = {0.f,0.f,0.f,0.f}, C1 = {0.f,0.f,0.f,0.f};
        f32x4 C2 = {0.f,0.f,0.f,0.f}, C3 = {0.f,0.f,0.f,0.f};
#pragma unroll
        for (int p = 0; p < 3; ++p) {
            const int ko = p * 32 + (lane >> 4) * 8;
            const s16x8 A  = *(const s16x8*)&Sw[(lane & 15) * PITCH_US + ko];
            const s16x8 B0 = *(const s16x8*)&Wbf[( 0 + (lane & 15)) * PITCH_US + ko];
            const s16x8 B1 = *(const s16x8*)&Wbf[(16 + (lane & 15)) * PITCH_US + ko];
            const s16x8 B2 = *(const s16x8*)&Wbf[(32 + (lane & 15)) * PITCH_US + ko];
            const s16x8 B3 = *(const s16x8*)&Wbf[(48 + (lane & 15)) * PITCH_US + ko];
            C0 = __builtin_amdgcn_mfma_f32_16x16x32_bf16(A, B0, C0, 0, 0, 0);
            C1 = __builtin_amdgcn_mfma_f32_16x16x32_bf16(A, B1, C1, 0, 0, 0);
            C2 = __builtin_amdgcn_mfma_f32_16x16x32_bf16(A, B2, C2, 0, 0, 0);
            C3 = __builtin_amdgcn_mfma_f32_16x16x32_bf16(A, B3, C3, 0, 0, 0);
        }

        // ---- epilogue: C/D layout col=lane&15, row=(lane>>4)*4+r ----
        const float bias0 = bvec[ 0 + (lane & 15)];
        const float bias1 = bvec[16 + (lane & 15)];
        const float bias2 = bvec[32 + (lane & 15)];
        const float bias3 = bvec[48 + (lane & 15)];
        const int m0 = (lane >> 4) * 4;
        const int oc = lane & 15;
#pragma unroll
        for (int r = 0; r < 4; ++r) {
            const size_t orow = ((size_t)b * KK + (size_t)(kg + m0 + r)) * OUTC;
            out[orow + 0  + oc] = fmaxf(C0[r] + bias0, 0.0f);
            out[orow + 16 + oc] = fmaxf(C1[r] + bias1, 0.0f);
            out[orow + 32 + oc] = fmaxf(C2[r] + bias2, 0.0f);
            out[orow + 48 + oc] = fmaxf(C3[r] + bias3, 0.0f);
        }
    }
}

extern "C" void kernel_launch(void* const* d_in, const int* in_sizes, int n_in,
                              void* d_out, int out_size, void* d_ws, size_t ws_size,
                              hipStream_t stream) {
    // setup_inputs order: keys(0), points(1), feats(2), n_idxs(3),
    // neighbor_rel(4), neighbor_valid(5), W(6), b(7). keys/points unused.
    const float* feats = (const float*)d_in[2];
    const int*   nidx  = (const int*)  d_in[3];
    const float* nrel  = (const float*)d_in[4];
    const int*   nval  = (const int*)  d_in[5];
    const float* Wm    = (const float*)d_in[6];
    const float* bv    = (const float*)d_in[7];
    float* out = (float*)d_out;

    // 1024 blocks = 128/batch (b = blockIdx&7 -> XCD binding), exact-fit
    // 4 blocks/CU (launch_bounds(256,4), LDS 26.6KB x4 = 106KB): no tail.
    // 4 waves x 32 rows x 1024 blocks = 131072 rows.
    graphconv_kernel<<<dim3(1024), dim3(256), 0, stream>>>(
        feats, nidx, nrel, nval, Wm, bv, out);
}

// Round 9
// 157.083 us; speedup vs baseline: 1.1693x; 1.0272x over previous
//
#include <hip/hip_runtime.h>

// Problem constants (from reference setup_inputs)
#define BB   8
#define PP   16384
#define KK   16384
#define NN   16
#define CIN  64
#define REL  3
#define CC   67
#define OUTC 64
#define PITCH_US 104       // ushorts per staged row: 96 data + 8 pad = 208 B

// History: r2-4 94us (W re-read from LDS per row); r5 76us (MFMA matvec);
// r6 87us regression (grid tail); r7 61us (quad-row dwordx4 gather, 4x fewer
// VMEM instrs). r7 counters: VALU 22%, HBM 24%, occ 33% -> wall is 4.5x
// issue time; VGPR_Count=52 proves the compiler kept only 1-2 gather results
// live, serializing the 16 gathers per quad (~13k cyc stall/quad = the gap).
// r8: compile error only (ds_swizzle pattern must be a constant int) --
// fixed here via template parameter; logic identical to the r8 plan.
//
// Round 8b: FORCE memory-level parallelism.
//  * all 4 quads' metadata loaded at group start (off the critical chain)
//  * all 16 bpermute results materialized in cm[16] BEFORE any gather
//  * gathers issued in two explicit batches of 8 float4 (32 VGPRs live),
//    __builtin_amdgcn_sched_barrier(0) after each issue-batch so the
//    scheduler cannot sink loads into the fma chain (r2-r7 lesson: the
//    allocator aggressively shrinks live state unless forbidden).
// Verified keepers: quad-row gather (lane = sub*16+q), bpermute broadcast,
// ds_swizzle segment butterfly, bf16 MFMA phase 2 (absmax 0.0156 vs 0.0725),
// XCD<->batch binding, exact-fit 1024-block grid (4 blocks/CU, no tail).

typedef short s16x8 __attribute__((ext_vector_type(8)));   // 8 bf16 = 4 VGPRs
typedef float f32x4 __attribute__((ext_vector_type(4)));   // MFMA accum
typedef unsigned int u32x2 __attribute__((ext_vector_type(2)));

static __device__ __forceinline__ unsigned short bf16_rne(float f) {
    unsigned int u = __float_as_uint(f);
    u += 0x7FFF + ((u >> 16) & 1);          // round-to-nearest-even
    return (unsigned short)(u >> 16);
}

template <int PAT>
static __device__ __forceinline__ float swz_add(float v) {
    return v + __int_as_float(
        __builtin_amdgcn_ds_swizzle(__float_as_int(v), PAT));
}

__global__ __launch_bounds__(256, 4) void graphconv_kernel(
    const float* __restrict__ feats,         // [B, P, CIN]
    const int*   __restrict__ n_idxs,        // [B, K, N]
    const float* __restrict__ neighbor_rel,  // [B, K, N, REL]
    const int*   __restrict__ neighbor_valid,// [B, K, N]
    const float* __restrict__ Wm,            // [OUTC, CC]
    const float* __restrict__ bvec,          // [OUTC]
    float*       __restrict__ out)           // [B, K, OUTC]
{
    __shared__ __align__(16) unsigned short Wbf[OUTC * PITCH_US];     // 13312 B
    __shared__ __align__(16) unsigned short Stile[4 * 16 * PITCH_US]; // 13312 B

    const int tid = threadIdx.x;

    // ---- one-time: W -> bf16 into LDS, B-layout, cols 67..95 zeroed ----
    {
        unsigned int* w32 = (unsigned int*)Wbf;
        for (int j = tid; j < OUTC * (PITCH_US / 2); j += 256) {
            const int o = j / (PITCH_US / 2);
            const int d = j - o * (PITCH_US / 2);
            const int c0 = 2 * d, c1 = 2 * d + 1;
            const float w0 = (c0 < CC) ? Wm[o * CC + c0] : 0.0f;
            const float w1 = (c1 < CC) ? Wm[o * CC + c1] : 0.0f;
            w32[j] = (unsigned int)bf16_rne(w0) |
                     ((unsigned int)bf16_rne(w1) << 16);
        }
    }
    __syncthreads();

    const int lane = tid & 63;
    const int wave = __builtin_amdgcn_readfirstlane(tid >> 6);
    unsigned short* Sw = &Stile[wave * 16 * PITCH_US];

    // zero own tile once (pad cols 68..95 must stay 0.0 for the MFMA)
    {
        unsigned int* s32 = (unsigned int*)Sw;
        for (int j = lane; j < 16 * (PITCH_US / 2); j += 64) s32[j] = 0u;
    }

    const int b   = blockIdx.x & 7;          // XCD-bound batch (verified)
    const int bib = blockIdx.x >> 3;
    const float* fb = feats + (size_t)b * ((size_t)PP * CIN);

    const int q     = lane & 15;             // channel quarter (cols 4q..4q+3)
    const int permb = (lane & 48) << 2;      // byte index of segment start

    const int kw = (bib * 4 + wave) * 32;    // wave's first k (32 rows/wave)

    for (int g = 0; g < 2; ++g) {
        const int kg = kw + g * 16;
        const size_t rg = (size_t)b * KK + (size_t)kg;

        // ---- all 4 quads' metadata up-front (off the critical chain) ----
        int   vld[4], idd[4];
        float rl0[4], rl1[4], rl2[4];
#pragma unroll
        for (int qd = 0; qd < 4; ++qd) {
            const size_t rq = rg + (size_t)(qd * 4);
            vld[qd] = neighbor_valid[rq * NN + lane];   // 256B coalesced
            idd[qd] = n_idxs[rq * NN + lane];           // 256B coalesced
            const float* relq = neighbor_rel + rq * (NN * REL);
            rl0[qd] = relq[3 * lane + 0];               // 768B coalesced
            rl1[qd] = relq[3 * lane + 1];
            rl2[qd] = relq[3 * lane + 2];
        }

        // ---- phase 1: 4 quads of 4 rows -> bf16 staging tile ----
        for (int qd = 0; qd < 4; ++qd) {
            const int   cmb = idd[qd] | (vld[qd] << 14);   // id<16384 fits
            const float msf = (float)vld[qd];
            float mr0 = msf * rl0[qd];
            float mr1 = msf * rl1[qd];
            float mr2 = msf * rl2[qd];
            float cnt = msf;

            // all 16 neighbor (id|mask) words first: one bpermute each
            int cm[NN];
#pragma unroll
            for (int n = 0; n < NN; ++n)
                cm[n] = __builtin_amdgcn_ds_bpermute(permb + 4 * n, cmb);

            float s0 = 0.f, s1 = 0.f, s2 = 0.f, s3 = 0.f;
            float4 gv[8];
#pragma unroll
            for (int h = 0; h < 2; ++h) {                // two batches of 8
#pragma unroll
                for (int n = 0; n < 8; ++n) {            // issue 8 gathers
                    const int off = ((cm[h * 8 + n] & 0x3FFF) << 6) + 4 * q;
                    gv[n] = *(const float4*)(fb + off);  // 16B/lane, in flight
                }
                __builtin_amdgcn_sched_barrier(0);        // loads stay hoisted
#pragma unroll
                for (int n = 0; n < 8; ++n) {            // consume 8
                    const float m = (float)(cm[h * 8 + n] >> 14);
                    s0 = fmaf(m, gv[n].x, s0);
                    s1 = fmaf(m, gv[n].y, s1);
                    s2 = fmaf(m, gv[n].z, s2);
                    s3 = fmaf(m, gv[n].w, s3);
                }
            }

            // segment(16-lane) butterfly: count + 3 masked rel sums
            cnt = swz_add<0x041F>(cnt); mr0 = swz_add<0x041F>(mr0);
            mr1 = swz_add<0x041F>(mr1); mr2 = swz_add<0x041F>(mr2);
            cnt = swz_add<0x081F>(cnt); mr0 = swz_add<0x081F>(mr0);
            mr1 = swz_add<0x081F>(mr1); mr2 = swz_add<0x081F>(mr2);
            cnt = swz_add<0x101F>(cnt); mr0 = swz_add<0x101F>(mr0);
            mr1 = swz_add<0x101F>(mr1); mr2 = swz_add<0x101F>(mr2);
            cnt = swz_add<0x201F>(cnt); mr0 = swz_add<0x201F>(mr0);
            mr1 = swz_add<0x201F>(mr1); mr2 = swz_add<0x201F>(mr2);

            const float inv = (cnt > 0.f) ? (1.0f / cnt) : 0.0f;

            const int rowl = qd * 4 + (lane >> 4);   // row within 16-row tile
            u32x2 pv;
            pv.x = (unsigned)bf16_rne(s0 * inv) |
                   ((unsigned)bf16_rne(s1 * inv) << 16);
            pv.y = (unsigned)bf16_rne(s2 * inv) |
                   ((unsigned)bf16_rne(s3 * inv) << 16);
            *(u32x2*)(&Sw[rowl * PITCH_US + 4 * q]) = pv;     // ds_write_b64
            if (q == 0) {                      // rel -> ch 64..66 (+0 pad 67)
                u32x2 ev;
                ev.x = (unsigned)bf16_rne(mr0 * inv) |
                       ((unsigned)bf16_rne(mr1 * inv) << 16);
                ev.y = (unsigned)bf16_rne(mr2 * inv);
                *(u32x2*)(&Sw[rowl * PITCH_US + 64]) = ev;
            }
        }

        // ---- phase 2: 16x64 = S(16x96) x W^T(96x64) on the MFMA pipe ----
        f32x4 C0 = {0.f,0.f,0.f,0.f}, C1 = {0.f,0.f,0.f,0.f};
        f32x4 C2 = {0.f,0.f,0.f,0.f}, C3 = {0.f,0.f,0.f,0.f};
#pragma unroll
        for (int p = 0; p < 3; ++p) {
            const int ko = p * 32 + (lane >> 4) * 8;
            const s16x8 A  = *(const s16x8*)&Sw[(lane & 15) * PITCH_US + ko];
            const s16x8 B0 = *(const s16x8*)&Wbf[( 0 + (lane & 15)) * PITCH_US + ko];
            const s16x8 B1 = *(const s16x8*)&Wbf[(16 + (lane & 15)) * PITCH_US + ko];
            const s16x8 B2 = *(const s16x8*)&Wbf[(32 + (lane & 15)) * PITCH_US + ko];
            const s16x8 B3 = *(const s16x8*)&Wbf[(48 + (lane & 15)) * PITCH_US + ko];
            C0 = __builtin_amdgcn_mfma_f32_16x16x32_bf16(A, B0, C0, 0, 0, 0);
            C1 = __builtin_amdgcn_mfma_f32_16x16x32_bf16(A, B1, C1, 0, 0, 0);
            C2 = __builtin_amdgcn_mfma_f32_16x16x32_bf16(A, B2, C2, 0, 0, 0);
            C3 = __builtin_amdgcn_mfma_f32_16x16x32_bf16(A, B3, C3, 0, 0, 0);
        }

        // ---- epilogue: C/D layout col=lane&15, row=(lane>>4)*4+r ----
        const float bias0 = bvec[ 0 + (lane & 15)];
        const float bias1 = bvec[16 + (lane & 15)];
        const float bias2 = bvec[32 + (lane & 15)];
        const float bias3 = bvec[48 + (lane & 15)];
        const int m0 = (lane >> 4) * 4;
        const int oc = lane & 15;
#pragma unroll
        for (int r = 0; r < 4; ++r) {
            const size_t orow = ((size_t)b * KK + (size_t)(kg + m0 + r)) * OUTC;
            out[orow + 0  + oc] = fmaxf(C0[r] + bias0, 0.0f);
            out[orow + 16 + oc] = fmaxf(C1[r] + bias1, 0.0f);
            out[orow + 32 + oc] = fmaxf(C2[r] + bias2, 0.0f);
            out[orow + 48 + oc] = fmaxf(C3[r] + bias3, 0.0f);
        }
    }
}

extern "C" void kernel_launch(void* const* d_in, const int* in_sizes, int n_in,
                              void* d_out, int out_size, void* d_ws, size_t ws_size,
                              hipStream_t stream) {
    // setup_inputs order: keys(0), points(1), feats(2), n_idxs(3),
    // neighbor_rel(4), neighbor_valid(5), W(6), b(7). keys/points unused.
    const float* feats = (const float*)d_in[2];
    const int*   nidx  = (const int*)  d_in[3];
    const float* nrel  = (const float*)d_in[4];
    const int*   nval  = (const int*)  d_in[5];
    const float* Wm    = (const float*)d_in[6];
    const float* bv    = (const float*)d_in[7];
    float* out = (float*)d_out;

    // 1024 blocks = 128/batch (b = blockIdx&7 -> XCD binding), exact-fit
    // 4 blocks/CU (launch_bounds(256,4), LDS 26.6KB x4 = 106KB): no tail.
    // 4 waves x 32 rows x 1024 blocks = 131072 rows.
    graphconv_kernel<<<dim3(1024), dim3(256), 0, stream>>>(
        feats, nidx, nrel, nval, Wm, bv, out);
}

// Round 10
// 155.620 us; speedup vs baseline: 1.1803x; 1.0094x over previous
//
#include <hip/hip_runtime.h>

// Problem constants (from reference setup_inputs)
#define BB   8
#define PP   16384
#define KK   16384
#define NN   16
#define CIN  64
#define REL  3
#define CC   67
#define OUTC 64
#define PITCH_US 104       // ushorts per staged row: 96 data + 8 pad = 208 B

// History: r2-4 94us (W re-read per row); r5 76us (MFMA matvec); r6 87us
// (grid tail regression); r7 61us (quad-row dwordx4 gather); r9 56us (16
// bpermutes + 8-wide gather batches; VGPR 52->64). r9 counters: VALU 24%,
// HBM 26%, MFMA 1%, occ 32% -- all pipes idle WITH ~128 CLs in flight per
// wave => the limiter is the per-CU outstanding-request pool (TCP/MSHR):
// 2048 gather instrs/CU x 16 CL each = 32k L2 reqs; at ~64 MSHR / ~300cyc
// L2 latency -> 0.21 CL/cyc -> 150k cyc = the measured wall. Only FEWER
// CACHELINES can move this.
//
// Round 10: bf16 feats pre-pass (HBM-bound, ~8us) -> main kernel gathers
// ushort4 (8 B/lane): feat row 256->128 B, 8 CLs per quad-gather instr
// (2x fewer), 16k CL/CU -> predicted ~31us main. Batch slab 4->2 MB also
// doubles L2 residency headroom. Accumulation stays fp32; one extra bf16
// rounding on inputs (they fed a bf16 MFMA anyway).
// Verified keepers: quad-row gather (lane = sub*16+q), bpermute broadcast,
// ds_swizzle butterfly, bf16 MFMA phase 2, XCD<->batch binding, exact-fit
// 1024-block grid (4 blocks/CU).

typedef short s16x8 __attribute__((ext_vector_type(8)));   // 8 bf16 = 4 VGPRs
typedef float f32x4 __attribute__((ext_vector_type(4)));   // MFMA accum
typedef unsigned int u32x2 __attribute__((ext_vector_type(2)));

static __device__ __forceinline__ unsigned short bf16_rne(float f) {
    unsigned int u = __float_as_uint(f);
    u += 0x7FFF + ((u >> 16) & 1);          // round-to-nearest-even
    return (unsigned short)(u >> 16);
}

template <int PAT>
static __device__ __forceinline__ float swz_add(float v) {
    return v + __int_as_float(
        __builtin_amdgcn_ds_swizzle(__float_as_int(v), PAT));
}

// ---- pre-pass: feats fp32 -> bf16 (RNE) into workspace ----
__global__ __launch_bounds__(256) void feats_to_bf16_kernel(
    const float* __restrict__ f, unsigned short* __restrict__ o)
{
    const int i = blockIdx.x * 256 + threadIdx.x;   // one float4 per thread
    const float4 v = ((const float4*)f)[i];         // 16B coalesced read
    ushort4 r;
    r.x = bf16_rne(v.x); r.y = bf16_rne(v.y);
    r.z = bf16_rne(v.z); r.w = bf16_rne(v.w);
    ((ushort4*)o)[i] = r;                           // 8B coalesced write
}

__global__ __launch_bounds__(256, 4) void graphconv_kernel(
    const unsigned short* __restrict__ fbf16,// [B, P, CIN] bf16 (workspace)
    const int*   __restrict__ n_idxs,        // [B, K, N]
    const float* __restrict__ neighbor_rel,  // [B, K, N, REL]
    const int*   __restrict__ neighbor_valid,// [B, K, N]
    const float* __restrict__ Wm,            // [OUTC, CC]
    const float* __restrict__ bvec,          // [OUTC]
    float*       __restrict__ out)           // [B, K, OUTC]
{
    __shared__ __align__(16) unsigned short Wbf[OUTC * PITCH_US];     // 13312 B
    __shared__ __align__(16) unsigned short Stile[4 * 16 * PITCH_US]; // 13312 B

    const int tid = threadIdx.x;

    // ---- one-time: W -> bf16 into LDS, B-layout, cols 67..95 zeroed ----
    {
        unsigned int* w32 = (unsigned int*)Wbf;
        for (int j = tid; j < OUTC * (PITCH_US / 2); j += 256) {
            const int o = j / (PITCH_US / 2);
            const int d = j - o * (PITCH_US / 2);
            const int c0 = 2 * d, c1 = 2 * d + 1;
            const float w0 = (c0 < CC) ? Wm[o * CC + c0] : 0.0f;
            const float w1 = (c1 < CC) ? Wm[o * CC + c1] : 0.0f;
            w32[j] = (unsigned int)bf16_rne(w0) |
                     ((unsigned int)bf16_rne(w1) << 16);
        }
    }
    __syncthreads();

    const int lane = tid & 63;
    const int wave = __builtin_amdgcn_readfirstlane(tid >> 6);
    unsigned short* Sw = &Stile[wave * 16 * PITCH_US];

    // zero own tile once (pad cols 68..95 must stay 0.0 for the MFMA)
    {
        unsigned int* s32 = (unsigned int*)Sw;
        for (int j = lane; j < 16 * (PITCH_US / 2); j += 64) s32[j] = 0u;
    }

    const int b   = blockIdx.x & 7;          // XCD-bound batch (verified)
    const int bib = blockIdx.x >> 3;
    const unsigned short* fb = fbf16 + (size_t)b * ((size_t)PP * CIN);

    const int q     = lane & 15;             // channel quarter (cols 4q..4q+3)
    const int permb = (lane & 48) << 2;      // byte index of segment start

    const int kw = (bib * 4 + wave) * 32;    // wave's first k (32 rows/wave)

    for (int g = 0; g < 2; ++g) {
        const int kg = kw + g * 16;
        const size_t rg = (size_t)b * KK + (size_t)kg;

        // ---- all 4 quads' metadata up-front (off the critical chain) ----
        int   vld[4], idd[4];
        float rl0[4], rl1[4], rl2[4];
#pragma unroll
        for (int qd = 0; qd < 4; ++qd) {
            const size_t rq = rg + (size_t)(qd * 4);
            vld[qd] = neighbor_valid[rq * NN + lane];   // 256B coalesced
            idd[qd] = n_idxs[rq * NN + lane];           // 256B coalesced
            const float* relq = neighbor_rel + rq * (NN * REL);
            rl0[qd] = relq[3 * lane + 0];               // 768B coalesced
            rl1[qd] = relq[3 * lane + 1];
            rl2[qd] = relq[3 * lane + 2];
        }

        // ---- phase 1: 4 quads of 4 rows -> bf16 staging tile ----
        for (int qd = 0; qd < 4; ++qd) {
            const int   cmb = idd[qd] | (vld[qd] << 14);   // id<16384 fits
            const float msf = (float)vld[qd];
            float mr0 = msf * rl0[qd];
            float mr1 = msf * rl1[qd];
            float mr2 = msf * rl2[qd];
            float cnt = msf;

            // all 16 neighbor (id|mask) words first: one bpermute each
            int cm[NN];
#pragma unroll
            for (int n = 0; n < NN; ++n)
                cm[n] = __builtin_amdgcn_ds_bpermute(permb + 4 * n, cmb);

            // issue ALL 16 bf16 gathers (uint2 = 8B/lane; 32 VGPRs live);
            // each instr touches 4 rows x 128B = 8 CLs (was 16 with fp32)
            u32x2 gv[NN];
#pragma unroll
            for (int n = 0; n < NN; ++n) {
                const int off = ((cm[n] & 0x3FFF) << 6) + 4 * q; // ushort elems
                gv[n] = *(const u32x2*)(fb + off);
            }
            __builtin_amdgcn_sched_barrier(0);        // loads stay hoisted

            float s0 = 0.f, s1 = 0.f, s2 = 0.f, s3 = 0.f;
#pragma unroll
            for (int n = 0; n < NN; ++n) {            // unpack bf16 + fma
                const float m = (float)(cm[n] >> 14);
                const unsigned ux = gv[n].x, uy = gv[n].y;
                s0 = fmaf(m, __uint_as_float(ux << 16), s0);
                s1 = fmaf(m, __uint_as_float(ux & 0xFFFF0000u), s1);
                s2 = fmaf(m, __uint_as_float(uy << 16), s2);
                s3 = fmaf(m, __uint_as_float(uy & 0xFFFF0000u), s3);
            }

            // segment(16-lane) butterfly: count + 3 masked rel sums
            cnt = swz_add<0x041F>(cnt); mr0 = swz_add<0x041F>(mr0);
            mr1 = swz_add<0x041F>(mr1); mr2 = swz_add<0x041F>(mr2);
            cnt = swz_add<0x081F>(cnt); mr0 = swz_add<0x081F>(mr0);
            mr1 = swz_add<0x081F>(mr1); mr2 = swz_add<0x081F>(mr2);
            cnt = swz_add<0x101F>(cnt); mr0 = swz_add<0x101F>(mr0);
            mr1 = swz_add<0x101F>(mr1); mr2 = swz_add<0x101F>(mr2);
            cnt = swz_add<0x201F>(cnt); mr0 = swz_add<0x201F>(mr0);
            mr1 = swz_add<0x201F>(mr1); mr2 = swz_add<0x201F>(mr2);

            const float inv = (cnt > 0.f) ? (1.0f / cnt) : 0.0f;

            const int rowl = qd * 4 + (lane >> 4);   // row within 16-row tile
            u32x2 pv;
            pv.x = (unsigned)bf16_rne(s0 * inv) |
                   ((unsigned)bf16_rne(s1 * inv) << 16);
            pv.y = (unsigned)bf16_rne(s2 * inv) |
                   ((unsigned)bf16_rne(s3 * inv) << 16);
            *(u32x2*)(&Sw[rowl * PITCH_US + 4 * q]) = pv;     // ds_write_b64
            if (q == 0) {                      // rel -> ch 64..66 (+0 pad 67)
                u32x2 ev;
                ev.x = (unsigned)bf16_rne(mr0 * inv) |
                       ((unsigned)bf16_rne(mr1 * inv) << 16);
                ev.y = (unsigned)bf16_rne(mr2 * inv);
                *(u32x2*)(&Sw[rowl * PITCH_US + 64]) = ev;
            }
        }

        // ---- phase 2: 16x64 = S(16x96) x W^T(96x64) on the MFMA pipe ----
        f32x4 C0 = {0.f,0.f,0.f,0.f}, C1 = {0.f,0.f,0.f,0.f};
        f32x4 C2 = {0.f,0.f,0.f,0.f}, C3 = {0.f,0.f,0.f,0.f};
#pragma unroll
        for (int p = 0; p < 3; ++p) {
            const int ko = p * 32 + (lane >> 4) * 8;
            const s16x8 A  = *(const s16x8*)&Sw[(lane & 15) * PITCH_US + ko];
            const s16x8 B0 = *(const s16x8*)&Wbf[( 0 + (lane & 15)) * PITCH_US + ko];
            const s16x8 B1 = *(const s16x8*)&Wbf[(16 + (lane & 15)) * PITCH_US + ko];
            const s16x8 B2 = *(const s16x8*)&Wbf[(32 + (lane & 15)) * PITCH_US + ko];
            const s16x8 B3 = *(const s16x8*)&Wbf[(48 + (lane & 15)) * PITCH_US + ko];
            C0 = __builtin_amdgcn_mfma_f32_16x16x32_bf16(A, B0, C0, 0, 0, 0);
            C1 = __builtin_amdgcn_mfma_f32_16x16x32_bf16(A, B1, C1, 0, 0, 0);
            C2 = __builtin_amdgcn_mfma_f32_16x16x32_bf16(A, B2, C2, 0, 0, 0);
            C3 = __builtin_amdgcn_mfma_f32_16x16x32_bf16(A, B3, C3, 0, 0, 0);
        }

        // ---- epilogue: C/D layout col=lane&15, row=(lane>>4)*4+r ----
        const float bias0 = bvec[ 0 + (lane & 15)];
        const float bias1 = bvec[16 + (lane & 15)];
        const float bias2 = bvec[32 + (lane & 15)];
        const float bias3 = bvec[48 + (lane & 15)];
        const int m0 = (lane >> 4) * 4;
        const int oc = lane & 15;
#pragma unroll
        for (int r = 0; r < 4; ++r) {
            const size_t orow = ((size_t)b * KK + (size_t)(kg + m0 + r)) * OUTC;
            out[orow + 0  + oc] = fmaxf(C0[r] + bias0, 0.0f);
            out[orow + 16 + oc] = fmaxf(C1[r] + bias1, 0.0f);
            out[orow + 32 + oc] = fmaxf(C2[r] + bias2, 0.0f);
            out[orow + 48 + oc] = fmaxf(C3[r] + bias3, 0.0f);
        }
    }
}

extern "C" void kernel_launch(void* const* d_in, const int* in_sizes, int n_in,
                              void* d_out, int out_size, void* d_ws, size_t ws_size,
                              hipStream_t stream) {
    // setup_inputs order: keys(0), points(1), feats(2), n_idxs(3),
    // neighbor_rel(4), neighbor_valid(5), W(6), b(7). keys/points unused.
    const float* feats = (const float*)d_in[2];
    const int*   nidx  = (const int*)  d_in[3];
    const float* nrel  = (const float*)d_in[4];
    const int*   nval  = (const int*)  d_in[5];
    const float* Wm    = (const float*)d_in[6];
    const float* bv    = (const float*)d_in[7];
    float* out = (float*)d_out;

    // workspace: bf16 feats image, 8*16384*64*2 = 16.78 MB (re-written every
    // call; harness re-poisons ws, so no state carried between calls)
    unsigned short* fbf16 = (unsigned short*)d_ws;

    // pre-pass: 8.39M floats / 4 per thread = 2.097M threads = 8192 blocks
    feats_to_bf16_kernel<<<dim3(8192), dim3(256), 0, stream>>>(feats, fbf16);

    // main: 1024 blocks = 128/batch (b = blockIdx&7 -> XCD binding),
    // exact-fit 4 blocks/CU; 4 waves x 32 rows x 1024 blocks = 131072 rows.
    graphconv_kernel<<<dim3(1024), dim3(256), 0, stream>>>(
        fbf16, nidx, nrel, nval, Wm, bv, out);
}